// Round 18
// baseline (52.929 us; speedup 1.0000x reference)
//
#include <hip/hip_runtime.h>

#define D 256
#define W8 2048

// workspace float offsets
#define WSC_OFF     20736             // 21 contiguous section-weight rows [k][d]
#define BPART_OFF   26112             // 4*256 bias partials
#define TB16_OFF    27392             // bf16 table: 81 rows * 256 ushort
// rows 0..52 card (pre-scaled 1/7), 53..61 hero, 62..70 acting, 71..80 nump

typedef float nf4 __attribute__((ext_vector_type(4)));  // native vec (nontemporal store)

__device__ __forceinline__ void f4acc(float4& a, const float4 b) {
    a.x += b.x; a.y += b.y; a.z += b.z; a.w += b.w;
}
__device__ __forceinline__ void f4fma(float4& a, float v, const float4 b) {
    a.x += v * b.x; a.y += v * b.y; a.z += v * b.z; a.w += v * b.w;
}

__device__ __forceinline__ ushort bf16rne(float v) {
    const unsigned x = __float_as_uint(v);
    return (ushort)((x + 0x7fffu + ((x >> 16) & 1u)) >> 16);
}

__device__ __forceinline__ float4 bf16x4(const ushort4 u) {
    float4 v;
    v.x = __uint_as_float((unsigned)u.x << 16);
    v.y = __uint_as_float((unsigned)u.y << 16);
    v.z = __uint_as_float((unsigned)u.z << 16);
    v.w = __uint_as_float((unsigned)u.w << 16);
    return v;
}

// -------- fuse v5 (unchanged from R17 — measured win) -----------------------

__global__ __launch_bounds__(256) void fuse5_kernel(
    const float* __restrict__ combine_W,
    const float* __restrict__ card_t, const float* __restrict__ hero_t,
    const float* __restrict__ act_t,  const float* __restrict__ nump_t,
    const float* __restrict__ scalar_W, const float* __restrict__ scalar_b,
    const float* __restrict__ blind_W,  const float* __restrict__ blind_b,
    const float* __restrict__ bet_W,    const float* __restrict__ bet_b,
    const float* __restrict__ action_W, const float* __restrict__ action_b,
    float* __restrict__ ws)
{
    __shared__ float vsh[D];
    __shared__ float Wl[D * 33];

    const int job = blockIdx.x;   // 0..105
    const int tid = threadIdx.x;

    int wblk;
    float scale = 1.0f;
    int kind, orow;

    if (job < 81) {
        kind = 0; orow = job;
        const float* src;
        if (job < 53)      { src = card_t + job * D;        wblk = 0; scale = 1.0f / 7.0f; }
        else if (job < 62) { src = hero_t + (job - 53) * D; wblk = 1; }
        else if (job < 71) { src = act_t  + (job - 62) * D; wblk = 2; }
        else               { src = nump_t + (job - 71) * D; wblk = 6; }
        vsh[tid] = src[tid];
    } else if (job < 102) {
        kind = 1; orow = job - 81;
        const float* secW; int nk, k;
        if (orow < 2)       { secW = scalar_W; nk = 2; k = orow;      wblk = 3; }
        else if (orow < 11) { secW = bet_W;    nk = 9; k = orow - 2;  wblk = 4; }
        else if (orow < 19) { secW = action_W; nk = 8; k = orow - 11; wblk = 5; }
        else                { secW = blind_W;  nk = 2; k = orow - 19; wblk = 7; }
        vsh[tid] = secW[tid * nk + k];
    } else {
        kind = 2; orow = job - 102;
        const float* secB;
        switch (orow) {
            case 0:  secB = scalar_b; wblk = 3; break;
            case 1:  secB = bet_b;    wblk = 4; break;
            case 2:  secB = action_b; wblk = 5; break;
            default: secB = blind_b;  wblk = 7; break;
        }
        vsh[tid] = secB[tid];
    }

    const float* Wbase = combine_W + wblk * D;
    float acc = 0.f;

    for (int t = 0; t < 8; ++t) {
        const int k0 = t * 32;
        __syncthreads();
#pragma unroll
        for (int i = 0; i < 8; ++i) {
            const int fidx = tid + i * 256;
            const int dd = fidx >> 3;
            const int kq = (fidx & 7) * 4;
            const float4 w = *(const float4*)(Wbase + (size_t)dd * W8 + k0 + kq);
            float* p = Wl + dd * 33 + kq;
            p[0] = w.x; p[1] = w.y; p[2] = w.z; p[3] = w.w;
        }
        __syncthreads();
        const float* wrow = Wl + tid * 33;
#pragma unroll
        for (int kk = 0; kk < 32; kk += 4) {
            const float4 vv = *(const float4*)(vsh + k0 + kk);
            acc += wrow[kk]     * vv.x + wrow[kk + 1] * vv.y
                 + wrow[kk + 2] * vv.z + wrow[kk + 3] * vv.w;
        }
    }

    ushort* tb  = (ushort*)(ws + TB16_OFF);
    float*  wsl = ws + WSC_OFF;
    float*  bpl = ws + BPART_OFF;
    if (kind == 0)      tb[orow * D + tid] = bf16rne(acc * scale);
    else if (kind == 1) wsl[orow * D + tid] = acc;
    else                bpl[orow * D + tid] = acc;
}

// -------- G: gathers only — thin body, no LDS, max wave concurrency --------
// R17 analysis: fused embed = 656 cy/token vs ~300 modeled -> latency-bound
// at 16 waves/CU. This kernel is ~40 VGPR, 0 LDS -> 8 waves/SIMD; 10
// independent 8B gathers/token; write-only out (stays L2-hot for S).

#define G_BLOCKS 2048
#define G_THREADS 256

__global__ __launch_bounds__(G_THREADS) void gather_kernel(
    const int* __restrict__ cards,  const int* __restrict__ hero,
    const int* __restrict__ acting, const int* __restrict__ nump,
    const float* __restrict__ ws, float* __restrict__ out, int ntok)
{
    const int tid  = threadIdx.x;
    const int lane = tid & 63;
    const int wave = tid >> 6;
    const int d0 = lane * 4;

    const ushort* tbg = (const ushort*)(ws + TB16_OFF);

    const int gw = blockIdx.x * (G_THREADS / 64) + wave;
    const int nw = G_BLOCKS * (G_THREADS / 64);

    for (int tok = gw; tok < ntok; tok += nw) {
        const int* cp = cards + (size_t)tok * 7;
        float4 acc = bf16x4(*(const ushort4*)(tbg + cp[0] * D + d0));
#pragma unroll
        for (int j = 1; j < 7; ++j)
            f4acc(acc, bf16x4(*(const ushort4*)(tbg + cp[j] * D + d0)));
        f4acc(acc, bf16x4(*(const ushort4*)(tbg + (53 + hero[tok])   * D + d0)));
        f4acc(acc, bf16x4(*(const ushort4*)(tbg + (62 + acting[tok]) * D + d0)));
        f4acc(acc, bf16x4(*(const ushort4*)(tbg + (71 + nump[tok])   * D + d0)));
        *(float4*)(out + (size_t)tok * D + d0) = acc;   // regular store: keep L2-hot
    }
}

// -------- S: sections + bias + mask, RMW on out ----------------------------
// Streaming: contiguous feature loads, 21 LDS-row FMAs, out read-modify-write.
// No gathers -> short dependence chains; LDS 22.5 KB.

#define S_BLOCKS 1024
#define S_THREADS 256
#define WROWS 22

__global__ __launch_bounds__(S_THREADS) void section_kernel(
    const float* __restrict__ scalars, const float* __restrict__ blinds,
    const float* __restrict__ bets,    const float* __restrict__ action,
    const float* __restrict__ mask,    const float* __restrict__ combine_b,
    const float* __restrict__ ws, float* __restrict__ out, int ntok)
{
    __shared__ __align__(16) float wlds[WROWS * D];

    const int tid = threadIdx.x;
    {
        const float4* src = (const float4*)(ws + WSC_OFF);
        float4* dst = (float4*)wlds;
        for (int i = tid; i < 21 * (D / 4); i += S_THREADS) dst[i] = src[i];
        wlds[21 * D + tid] = combine_b[tid]
            + ws[BPART_OFF + 0 * D + tid] + ws[BPART_OFF + 1 * D + tid]
            + ws[BPART_OFF + 2 * D + tid] + ws[BPART_OFF + 3 * D + tid];
    }
    __syncthreads();

    const int lane = tid & 63;
    const int wave = tid >> 6;
    const int d0 = lane * 4;

    const int gw = blockIdx.x * (S_THREADS / 64) + wave;
    const int nw = S_BLOCKS * (S_THREADS / 64);

    for (int tok = gw; tok < ntok; tok += nw) {
        // RMW read of the gather partial (L2-hot from G)
        float4 acc0 = *(const float4*)(out + (size_t)tok * D + d0);
        f4acc(acc0, *(const float4*)(wlds + 21 * D + d0));   // + bias
        float4 acc1 = {0.f, 0.f, 0.f, 0.f};

        const float2 fs = *(const float2*)(scalars + (size_t)tok * 2);
        f4fma(acc1, fs.x, *(const float4*)(wlds + 0 * D + d0));
        f4fma(acc1, fs.y, *(const float4*)(wlds + 1 * D + d0));

        const float* fb = bets + (size_t)tok * 9;
#pragma unroll
        for (int k = 0; k < 9; ++k)
            f4fma(acc1, fb[k], *(const float4*)(wlds + (2 + k) * D + d0));

        const float4 fa0 = *(const float4*)(action + (size_t)tok * 8);
        const float4 fa1 = *(const float4*)(action + (size_t)tok * 8 + 4);
        f4fma(acc1, fa0.x, *(const float4*)(wlds + 11 * D + d0));
        f4fma(acc1, fa0.y, *(const float4*)(wlds + 12 * D + d0));
        f4fma(acc1, fa0.z, *(const float4*)(wlds + 13 * D + d0));
        f4fma(acc1, fa0.w, *(const float4*)(wlds + 14 * D + d0));
        f4fma(acc1, fa1.x, *(const float4*)(wlds + 15 * D + d0));
        f4fma(acc1, fa1.y, *(const float4*)(wlds + 16 * D + d0));
        f4fma(acc1, fa1.z, *(const float4*)(wlds + 17 * D + d0));
        f4fma(acc1, fa1.w, *(const float4*)(wlds + 18 * D + d0));

        const float2 fl = *(const float2*)(blinds + (size_t)tok * 2);
        f4fma(acc1, fl.x, *(const float4*)(wlds + 19 * D + d0));
        f4fma(acc1, fl.y, *(const float4*)(wlds + 20 * D + d0));

        const float m = mask[tok];
        nf4 o;
        o.x = (acc0.x + acc1.x) * m; o.y = (acc0.y + acc1.y) * m;
        o.z = (acc0.z + acc1.z) * m; o.w = (acc0.w + acc1.w) * m;
        __builtin_nontemporal_store(o, (nf4*)(out + (size_t)tok * D + d0));
    }
}

extern "C" void kernel_launch(void* const* d_in, const int* in_sizes, int n_in,
                              void* d_out, int out_size, void* d_ws, size_t ws_size,
                              hipStream_t stream) {
    const int*   cards    = (const int*)d_in[0];
    const int*   hero     = (const int*)d_in[1];
    const int*   acting   = (const int*)d_in[2];
    const int*   nump     = (const int*)d_in[3];
    const float* scalars  = (const float*)d_in[4];
    const float* blinds   = (const float*)d_in[5];
    const float* bets     = (const float*)d_in[6];
    const float* action   = (const float*)d_in[7];
    const float* mask     = (const float*)d_in[8];
    const float* card_t   = (const float*)d_in[9];
    const float* hero_t   = (const float*)d_in[10];
    const float* act_t    = (const float*)d_in[11];
    const float* nump_t   = (const float*)d_in[12];
    const float* scalar_W = (const float*)d_in[13];
    const float* scalar_b = (const float*)d_in[14];
    const float* blind_W  = (const float*)d_in[15];
    const float* blind_b  = (const float*)d_in[16];
    const float* bet_W    = (const float*)d_in[17];
    const float* bet_b    = (const float*)d_in[18];
    const float* action_W = (const float*)d_in[19];
    const float* action_b = (const float*)d_in[20];
    const float* combine_W= (const float*)d_in[21];
    const float* combine_b= (const float*)d_in[22];

    float* ws  = (float*)d_ws;
    float* out = (float*)d_out;
    const int ntok = in_sizes[1];  // B*S (hero_pos flat count)

    hipLaunchKernelGGL(fuse5_kernel, dim3(106), dim3(256), 0, stream,
                       combine_W, card_t, hero_t, act_t, nump_t,
                       scalar_W, scalar_b, blind_W, blind_b, bet_W, bet_b,
                       action_W, action_b, ws);
    hipLaunchKernelGGL(gather_kernel, dim3(G_BLOCKS), dim3(G_THREADS), 0, stream,
                       cards, hero, acting, nump, ws, out, ntok);
    hipLaunchKernelGGL(section_kernel, dim3(S_BLOCKS), dim3(S_THREADS), 0, stream,
                       scalars, blinds, bets, action, mask, combine_b, ws, out, ntok);
}

// Round 19
// 36.244 us; speedup vs baseline: 1.4604x; 1.4604x over previous
//
#include <hip/hip_runtime.h>

#define D 256
#define W8 2048

// workspace float offsets
#define WSC_OFF     20736             // 21 contiguous section-weight rows [k][d]
#define BPART_OFF   26112             // 4*256 bias partials
#define TB16_OFF    27392             // bf16 table: 81 rows * 256 ushort
// rows 0..52 card (pre-scaled 1/7), 53..61 hero, 62..70 acting, 71..80 nump

typedef float nf4 __attribute__((ext_vector_type(4)));  // native vec (nontemporal store)

__device__ __forceinline__ void f4acc(float4& a, const float4 b) {
    a.x += b.x; a.y += b.y; a.z += b.z; a.w += b.w;
}
__device__ __forceinline__ void f4fma(float4& a, float v, const float4 b) {
    a.x += v * b.x; a.y += v * b.y; a.z += v * b.z; a.w += v * b.w;
}

__device__ __forceinline__ ushort bf16rne(float v) {
    const unsigned x = __float_as_uint(v);
    return (ushort)((x + 0x7fffu + ((x >> 16) & 1u)) >> 16);
}

__device__ __forceinline__ float4 bf16x4(const ushort4 u) {
    float4 v;
    v.x = __uint_as_float((unsigned)u.x << 16);
    v.y = __uint_as_float((unsigned)u.y << 16);
    v.z = __uint_as_float((unsigned)u.z << 16);
    v.w = __uint_as_float((unsigned)u.w << 16);
    return v;
}

// -------- fuse v5 (unchanged from R17 — measured win) -----------------------

__global__ __launch_bounds__(256) void fuse5_kernel(
    const float* __restrict__ combine_W,
    const float* __restrict__ card_t, const float* __restrict__ hero_t,
    const float* __restrict__ act_t,  const float* __restrict__ nump_t,
    const float* __restrict__ scalar_W, const float* __restrict__ scalar_b,
    const float* __restrict__ blind_W,  const float* __restrict__ blind_b,
    const float* __restrict__ bet_W,    const float* __restrict__ bet_b,
    const float* __restrict__ action_W, const float* __restrict__ action_b,
    float* __restrict__ ws)
{
    __shared__ float vsh[D];
    __shared__ float Wl[D * 33];

    const int job = blockIdx.x;   // 0..105
    const int tid = threadIdx.x;

    int wblk;
    float scale = 1.0f;
    int kind, orow;

    if (job < 81) {
        kind = 0; orow = job;
        const float* src;
        if (job < 53)      { src = card_t + job * D;        wblk = 0; scale = 1.0f / 7.0f; }
        else if (job < 62) { src = hero_t + (job - 53) * D; wblk = 1; }
        else if (job < 71) { src = act_t  + (job - 62) * D; wblk = 2; }
        else               { src = nump_t + (job - 71) * D; wblk = 6; }
        vsh[tid] = src[tid];
    } else if (job < 102) {
        kind = 1; orow = job - 81;
        const float* secW; int nk, k;
        if (orow < 2)       { secW = scalar_W; nk = 2; k = orow;      wblk = 3; }
        else if (orow < 11) { secW = bet_W;    nk = 9; k = orow - 2;  wblk = 4; }
        else if (orow < 19) { secW = action_W; nk = 8; k = orow - 11; wblk = 5; }
        else                { secW = blind_W;  nk = 2; k = orow - 19; wblk = 7; }
        vsh[tid] = secW[tid * nk + k];
    } else {
        kind = 2; orow = job - 102;
        const float* secB;
        switch (orow) {
            case 0:  secB = scalar_b; wblk = 3; break;
            case 1:  secB = bet_b;    wblk = 4; break;
            case 2:  secB = action_b; wblk = 5; break;
            default: secB = blind_b;  wblk = 7; break;
        }
        vsh[tid] = secB[tid];
    }

    const float* Wbase = combine_W + wblk * D;
    float acc = 0.f;

    for (int t = 0; t < 8; ++t) {
        const int k0 = t * 32;
        __syncthreads();
#pragma unroll
        for (int i = 0; i < 8; ++i) {
            const int fidx = tid + i * 256;
            const int dd = fidx >> 3;
            const int kq = (fidx & 7) * 4;
            const float4 w = *(const float4*)(Wbase + (size_t)dd * W8 + k0 + kq);
            float* p = Wl + dd * 33 + kq;
            p[0] = w.x; p[1] = w.y; p[2] = w.z; p[3] = w.w;
        }
        __syncthreads();
        const float* wrow = Wl + tid * 33;
#pragma unroll
        for (int kk = 0; kk < 32; kk += 4) {
            const float4 vv = *(const float4*)(vsh + k0 + kk);
            acc += wrow[kk]     * vv.x + wrow[kk + 1] * vv.y
                 + wrow[kk + 2] * vv.z + wrow[kk + 3] * vv.w;
        }
    }

    ushort* tb  = (ushort*)(ws + TB16_OFF);
    float*  wsl = ws + WSC_OFF;
    float*  bpl = ws + BPART_OFF;
    if (kind == 0)      tb[orow * D + tid] = bf16rne(acc * scale);
    else if (kind == 1) wsl[orow * D + tid] = acc;
    else                bpl[orow * D + tid] = acc;
}

// -------- main: R17 body, CONTIGUOUS tokens per wave (single variable) ------
// R18 lesson: kernel split costs an out round-trip (+15us) — fused stays.
// Hypothesis: grid-stride (token stride 4096) scatters NT writes into
// isolated 1KB chunks from 4096 waves (hbm ~800 GB/s observed -> 32MB = 40us)
// and defeats index/feature cache-line reuse. Here wave w owns tokens
// [w*8, w*8+8): sequential 8KB write stream, shared index/feature lines.
// Body per token is byte-identical to R17. VGPR-neutral.

#define EMB_BLOCKS 1024
#define EMB_THREADS 256
#define EMB_WAVES (EMB_THREADS / 64)
#define TPW 8     // contiguous tokens per wave
#define WROWS 22  // 21 weight rows + 1 fused-bias row

__global__ __launch_bounds__(EMB_THREADS) void embed_kernel(
    const int* __restrict__ cards,  const int* __restrict__ hero,
    const int* __restrict__ acting, const int* __restrict__ nump,
    const float* __restrict__ scalars, const float* __restrict__ blinds,
    const float* __restrict__ bets,    const float* __restrict__ action,
    const float* __restrict__ mask,    const float* __restrict__ combine_b,
    const float* __restrict__ ws, float* __restrict__ out, int ntok)
{
    __shared__ __align__(16) float wlds[WROWS * D];  // 22528 B

    const int tid = threadIdx.x;

    {
        const float4* src = (const float4*)(ws + WSC_OFF);
        float4* dst = (float4*)wlds;
        for (int i = tid; i < 21 * (D / 4); i += EMB_THREADS) dst[i] = src[i];
        wlds[21 * D + tid] = combine_b[tid]
            + ws[BPART_OFF + 0 * D + tid] + ws[BPART_OFF + 1 * D + tid]
            + ws[BPART_OFF + 2 * D + tid] + ws[BPART_OFF + 3 * D + tid];
    }
    __syncthreads();

    const int lane = tid & 63;
    const int wave = tid >> 6;
    const int d0 = lane * 4;

    const ushort* tbg = (const ushort*)(ws + TB16_OFF);

    const int gw = blockIdx.x * EMB_WAVES + wave;
    const int base = gw * TPW;

    for (int i = 0; i < TPW; ++i) {
        const int tok = base + i;
        if (tok >= ntok) break;

        float4 acc0 = *(const float4*)(wlds + 21 * D + d0);  // bias + gathers
        float4 acc1 = {0.f, 0.f, 0.f, 0.f};                  // sections

        const int* cp = cards + (size_t)tok * 7;
#pragma unroll
        for (int j = 0; j < 7; ++j)
            f4acc(acc0, bf16x4(*(const ushort4*)(tbg + cp[j] * D + d0)));
        f4acc(acc0, bf16x4(*(const ushort4*)(tbg + (53 + hero[tok])   * D + d0)));
        f4acc(acc0, bf16x4(*(const ushort4*)(tbg + (62 + acting[tok]) * D + d0)));
        f4acc(acc0, bf16x4(*(const ushort4*)(tbg + (71 + nump[tok])   * D + d0)));

        const float2 fs = *(const float2*)(scalars + (size_t)tok * 2);
        f4fma(acc1, fs.x, *(const float4*)(wlds + 0 * D + d0));
        f4fma(acc1, fs.y, *(const float4*)(wlds + 1 * D + d0));

        const float* fb = bets + (size_t)tok * 9;
#pragma unroll
        for (int k = 0; k < 9; ++k)
            f4fma(acc1, fb[k], *(const float4*)(wlds + (2 + k) * D + d0));

        const float4 fa0 = *(const float4*)(action + (size_t)tok * 8);
        const float4 fa1 = *(const float4*)(action + (size_t)tok * 8 + 4);
        f4fma(acc1, fa0.x, *(const float4*)(wlds + 11 * D + d0));
        f4fma(acc1, fa0.y, *(const float4*)(wlds + 12 * D + d0));
        f4fma(acc1, fa0.z, *(const float4*)(wlds + 13 * D + d0));
        f4fma(acc1, fa0.w, *(const float4*)(wlds + 14 * D + d0));
        f4fma(acc1, fa1.x, *(const float4*)(wlds + 15 * D + d0));
        f4fma(acc1, fa1.y, *(const float4*)(wlds + 16 * D + d0));
        f4fma(acc1, fa1.z, *(const float4*)(wlds + 17 * D + d0));
        f4fma(acc1, fa1.w, *(const float4*)(wlds + 18 * D + d0));

        const float2 fl = *(const float2*)(blinds + (size_t)tok * 2);
        f4fma(acc1, fl.x, *(const float4*)(wlds + 19 * D + d0));
        f4fma(acc1, fl.y, *(const float4*)(wlds + 20 * D + d0));

        const float m = mask[tok];
        nf4 o;
        o.x = (acc0.x + acc1.x) * m; o.y = (acc0.y + acc1.y) * m;
        o.z = (acc0.z + acc1.z) * m; o.w = (acc0.w + acc1.w) * m;
        __builtin_nontemporal_store(o, (nf4*)(out + (size_t)tok * D + d0));
    }
}

extern "C" void kernel_launch(void* const* d_in, const int* in_sizes, int n_in,
                              void* d_out, int out_size, void* d_ws, size_t ws_size,
                              hipStream_t stream) {
    const int*   cards    = (const int*)d_in[0];
    const int*   hero     = (const int*)d_in[1];
    const int*   acting   = (const int*)d_in[2];
    const int*   nump     = (const int*)d_in[3];
    const float* scalars  = (const float*)d_in[4];
    const float* blinds   = (const float*)d_in[5];
    const float* bets     = (const float*)d_in[6];
    const float* action   = (const float*)d_in[7];
    const float* mask     = (const float*)d_in[8];
    const float* card_t   = (const float*)d_in[9];
    const float* hero_t   = (const float*)d_in[10];
    const float* act_t    = (const float*)d_in[11];
    const float* nump_t   = (const float*)d_in[12];
    const float* scalar_W = (const float*)d_in[13];
    const float* scalar_b = (const float*)d_in[14];
    const float* blind_W  = (const float*)d_in[15];
    const float* blind_b  = (const float*)d_in[16];
    const float* bet_W    = (const float*)d_in[17];
    const float* bet_b    = (const float*)d_in[18];
    const float* action_W = (const float*)d_in[19];
    const float* action_b = (const float*)d_in[20];
    const float* combine_W= (const float*)d_in[21];
    const float* combine_b= (const float*)d_in[22];

    float* ws  = (float*)d_ws;
    float* out = (float*)d_out;
    const int ntok = in_sizes[1];  // B*S (hero_pos flat count)

    hipLaunchKernelGGL(fuse5_kernel, dim3(106), dim3(256), 0, stream,
                       combine_W, card_t, hero_t, act_t, nump_t,
                       scalar_W, scalar_b, blind_W, blind_b, bet_W, bet_b,
                       action_W, action_b, ws);
    hipLaunchKernelGGL(embed_kernel, dim3(EMB_BLOCKS), dim3(EMB_THREADS), 0, stream,
                       cards, hero, acting, nump, scalars, blinds, bets, action, mask,
                       combine_b, ws, out, ntok);
}

// Round 20
// 35.936 us; speedup vs baseline: 1.4729x; 1.0086x over previous
//
#include <hip/hip_runtime.h>

#define D 256
#define W8 2048

// workspace float offsets
#define WSC_OFF     20736             // 21 contiguous section-weight rows [k][d]
#define BPART_OFF   26112             // 4*256 bias partials
#define TB16_OFF    27392             // bf16 table: 81 rows * 256 ushort
// rows 0..52 card (pre-scaled 1/7), 53..61 hero, 62..70 acting, 71..80 nump

typedef float nf4 __attribute__((ext_vector_type(4)));  // native vec (nontemporal store)

__device__ __forceinline__ void f4acc(float4& a, const float4 b) {
    a.x += b.x; a.y += b.y; a.z += b.z; a.w += b.w;
}
__device__ __forceinline__ void f4fma(float4& a, float v, const float4 b) {
    a.x += v * b.x; a.y += v * b.y; a.z += v * b.z; a.w += v * b.w;
}

__device__ __forceinline__ ushort bf16rne(float v) {
    const unsigned x = __float_as_uint(v);
    return (ushort)((x + 0x7fffu + ((x >> 16) & 1u)) >> 16);
}

__device__ __forceinline__ float4 bf16x4(const ushort4 u) {
    float4 v;
    v.x = __uint_as_float((unsigned)u.x << 16);
    v.y = __uint_as_float((unsigned)u.y << 16);
    v.z = __uint_as_float((unsigned)u.z << 16);
    v.w = __uint_as_float((unsigned)u.w << 16);
    return v;
}

// -------- fuse v5 (unchanged from R17 — measured win) -----------------------

__global__ __launch_bounds__(256) void fuse5_kernel(
    const float* __restrict__ combine_W,
    const float* __restrict__ card_t, const float* __restrict__ hero_t,
    const float* __restrict__ act_t,  const float* __restrict__ nump_t,
    const float* __restrict__ scalar_W, const float* __restrict__ scalar_b,
    const float* __restrict__ blind_W,  const float* __restrict__ blind_b,
    const float* __restrict__ bet_W,    const float* __restrict__ bet_b,
    const float* __restrict__ action_W, const float* __restrict__ action_b,
    float* __restrict__ ws)
{
    __shared__ float vsh[D];
    __shared__ float Wl[D * 33];

    const int job = blockIdx.x;   // 0..105
    const int tid = threadIdx.x;

    int wblk;
    float scale = 1.0f;
    int kind, orow;

    if (job < 81) {
        kind = 0; orow = job;
        const float* src;
        if (job < 53)      { src = card_t + job * D;        wblk = 0; scale = 1.0f / 7.0f; }
        else if (job < 62) { src = hero_t + (job - 53) * D; wblk = 1; }
        else if (job < 71) { src = act_t  + (job - 62) * D; wblk = 2; }
        else               { src = nump_t + (job - 71) * D; wblk = 6; }
        vsh[tid] = src[tid];
    } else if (job < 102) {
        kind = 1; orow = job - 81;
        const float* secW; int nk, k;
        if (orow < 2)       { secW = scalar_W; nk = 2; k = orow;      wblk = 3; }
        else if (orow < 11) { secW = bet_W;    nk = 9; k = orow - 2;  wblk = 4; }
        else if (orow < 19) { secW = action_W; nk = 8; k = orow - 11; wblk = 5; }
        else                { secW = blind_W;  nk = 2; k = orow - 19; wblk = 7; }
        vsh[tid] = secW[tid * nk + k];
    } else {
        kind = 2; orow = job - 102;
        const float* secB;
        switch (orow) {
            case 0:  secB = scalar_b; wblk = 3; break;
            case 1:  secB = bet_b;    wblk = 4; break;
            case 2:  secB = action_b; wblk = 5; break;
            default: secB = blind_b;  wblk = 7; break;
        }
        vsh[tid] = secB[tid];
    }

    const float* Wbase = combine_W + wblk * D;
    float acc = 0.f;

    for (int t = 0; t < 8; ++t) {
        const int k0 = t * 32;
        __syncthreads();
#pragma unroll
        for (int i = 0; i < 8; ++i) {
            const int fidx = tid + i * 256;
            const int dd = fidx >> 3;
            const int kq = (fidx & 7) * 4;
            const float4 w = *(const float4*)(Wbase + (size_t)dd * W8 + k0 + kq);
            float* p = Wl + dd * 33 + kq;
            p[0] = w.x; p[1] = w.y; p[2] = w.z; p[3] = w.w;
        }
        __syncthreads();
        const float* wrow = Wl + tid * 33;
#pragma unroll
        for (int kk = 0; kk < 32; kk += 4) {
            const float4 vv = *(const float4*)(vsh + k0 + kk);
            acc += wrow[kk]     * vv.x + wrow[kk + 1] * vv.y
                 + wrow[kk + 2] * vv.z + wrow[kk + 3] * vv.w;
        }
    }

    ushort* tb  = (ushort*)(ws + TB16_OFF);
    float*  wsl = ws + WSC_OFF;
    float*  bpl = ws + BPART_OFF;
    if (kind == 0)      tb[orow * D + tid] = bf16rne(acc * scale);
    else if (kind == 1) wsl[orow * D + tid] = acc;
    else                bpl[orow * D + tid] = acc;
}

// -------- main: R19 body, SINGLE accumulator (target: VGPR <= 64 cliff) -----
// 19-round fact table: full-cost instruction sensitivity (R13) + occupancy
// sensitivity (R1/R7/R3) => issue/stall-composed at 4 waves/SIMD. 68 VGPR is
// 4 over the 64 cliff (m69). acc0/acc1 merge saves 4 VGPR + 4 adds; ILP loss
// is free if issue-bound. #pragma unroll 1 prevents unroll reg inflation.
// R11 lesson (3rd strike): never launch_bounds min-waves on this body.

#define EMB_BLOCKS 1024
#define EMB_THREADS 256
#define EMB_WAVES (EMB_THREADS / 64)
#define TPW 8     // contiguous tokens per wave (1024*4*8 = 32768 exact cover)
#define WROWS 22  // 21 weight rows + 1 fused-bias row

__global__ __launch_bounds__(EMB_THREADS) void embed_kernel(
    const int* __restrict__ cards,  const int* __restrict__ hero,
    const int* __restrict__ acting, const int* __restrict__ nump,
    const float* __restrict__ scalars, const float* __restrict__ blinds,
    const float* __restrict__ bets,    const float* __restrict__ action,
    const float* __restrict__ mask,    const float* __restrict__ combine_b,
    const float* __restrict__ ws, float* __restrict__ out, int ntok)
{
    __shared__ __align__(16) float wlds[WROWS * D];  // 22528 B

    const int tid = threadIdx.x;

    {
        const float4* src = (const float4*)(ws + WSC_OFF);
        float4* dst = (float4*)wlds;
        for (int i = tid; i < 21 * (D / 4); i += EMB_THREADS) dst[i] = src[i];
        wlds[21 * D + tid] = combine_b[tid]
            + ws[BPART_OFF + 0 * D + tid] + ws[BPART_OFF + 1 * D + tid]
            + ws[BPART_OFF + 2 * D + tid] + ws[BPART_OFF + 3 * D + tid];
    }
    __syncthreads();

    const int lane = tid & 63;
    const int wave = tid >> 6;
    const int d0 = lane * 4;

    const ushort* tbg = (const ushort*)(ws + TB16_OFF);

    const int gw = blockIdx.x * EMB_WAVES + wave;
    const int base = gw * TPW;

#pragma unroll 1
    for (int i = 0; i < TPW; ++i) {
        const int tok = base + i;
        if (tok >= ntok) break;

        float4 acc = *(const float4*)(wlds + 21 * D + d0);  // bias

        const int* cp = cards + (size_t)tok * 7;
#pragma unroll
        for (int j = 0; j < 7; ++j)
            f4acc(acc, bf16x4(*(const ushort4*)(tbg + cp[j] * D + d0)));
        f4acc(acc, bf16x4(*(const ushort4*)(tbg + (53 + hero[tok])   * D + d0)));
        f4acc(acc, bf16x4(*(const ushort4*)(tbg + (62 + acting[tok]) * D + d0)));
        f4acc(acc, bf16x4(*(const ushort4*)(tbg + (71 + nump[tok])   * D + d0)));

        const float2 fs = *(const float2*)(scalars + (size_t)tok * 2);
        f4fma(acc, fs.x, *(const float4*)(wlds + 0 * D + d0));
        f4fma(acc, fs.y, *(const float4*)(wlds + 1 * D + d0));

        const float* fb = bets + (size_t)tok * 9;
#pragma unroll
        for (int k = 0; k < 9; ++k)
            f4fma(acc, fb[k], *(const float4*)(wlds + (2 + k) * D + d0));

        const float4 fa0 = *(const float4*)(action + (size_t)tok * 8);
        const float4 fa1 = *(const float4*)(action + (size_t)tok * 8 + 4);
        f4fma(acc, fa0.x, *(const float4*)(wlds + 11 * D + d0));
        f4fma(acc, fa0.y, *(const float4*)(wlds + 12 * D + d0));
        f4fma(acc, fa0.z, *(const float4*)(wlds + 13 * D + d0));
        f4fma(acc, fa0.w, *(const float4*)(wlds + 14 * D + d0));
        f4fma(acc, fa1.x, *(const float4*)(wlds + 15 * D + d0));
        f4fma(acc, fa1.y, *(const float4*)(wlds + 16 * D + d0));
        f4fma(acc, fa1.z, *(const float4*)(wlds + 17 * D + d0));
        f4fma(acc, fa1.w, *(const float4*)(wlds + 18 * D + d0));

        const float2 fl = *(const float2*)(blinds + (size_t)tok * 2);
        f4fma(acc, fl.x, *(const float4*)(wlds + 19 * D + d0));
        f4fma(acc, fl.y, *(const float4*)(wlds + 20 * D + d0));

        const float m = mask[tok];
        nf4 o;
        o.x = acc.x * m; o.y = acc.y * m;
        o.z = acc.z * m; o.w = acc.w * m;
        __builtin_nontemporal_store(o, (nf4*)(out + (size_t)tok * D + d0));
    }
}

extern "C" void kernel_launch(void* const* d_in, const int* in_sizes, int n_in,
                              void* d_out, int out_size, void* d_ws, size_t ws_size,
                              hipStream_t stream) {
    const int*   cards    = (const int*)d_in[0];
    const int*   hero     = (const int*)d_in[1];
    const int*   acting   = (const int*)d_in[2];
    const int*   nump     = (const int*)d_in[3];
    const float* scalars  = (const float*)d_in[4];
    const float* blinds   = (const float*)d_in[5];
    const float* bets     = (const float*)d_in[6];
    const float* action   = (const float*)d_in[7];
    const float* mask     = (const float*)d_in[8];
    const float* card_t   = (const float*)d_in[9];
    const float* hero_t   = (const float*)d_in[10];
    const float* act_t    = (const float*)d_in[11];
    const float* nump_t   = (const float*)d_in[12];
    const float* scalar_W = (const float*)d_in[13];
    const float* scalar_b = (const float*)d_in[14];
    const float* blind_W  = (const float*)d_in[15];
    const float* blind_b  = (const float*)d_in[16];
    const float* bet_W    = (const float*)d_in[17];
    const float* bet_b    = (const float*)d_in[18];
    const float* action_W = (const float*)d_in[19];
    const float* action_b = (const float*)d_in[20];
    const float* combine_W= (const float*)d_in[21];
    const float* combine_b= (const float*)d_in[22];

    float* ws  = (float*)d_ws;
    float* out = (float*)d_out;
    const int ntok = in_sizes[1];  // B*S (hero_pos flat count)

    hipLaunchKernelGGL(fuse5_kernel, dim3(106), dim3(256), 0, stream,
                       combine_W, card_t, hero_t, act_t, nump_t,
                       scalar_W, scalar_b, blind_W, blind_b, bet_W, bet_b,
                       action_W, action_b, ws);
    hipLaunchKernelGGL(embed_kernel, dim3(EMB_BLOCKS), dim3(EMB_THREADS), 0, stream,
                       cards, hero, acting, nump, scalars, blinds, bets, action, mask,
                       combine_b, ws, out, ntok);
}